// Round 7
// baseline (289.217 us; speedup 1.0000x reference)
//
#include <hip/hip_runtime.h>
#include <math.h>

// Problem constants: B=4,S=4096,IN=2048,E=16,D=128,A=128,R=4
#define NTOK   16384
#define INDIM  2048
#define NROWS  20      // 16 Wv rows + 4 mlp_w1 rows
#define CHUNK  256     // K-chunk (floats) in the main loop; 8 chunks

// workspace (float) layout (precompute tables)
#define WS_PKT  0
#define WS_D1K  1024
#define WS_GQK  1280
#define WS_BQK  1536
#define WS_SCAL 1792
#define WS_TOT  1818

#define SIM_SCALE 0.08838834764831845f  // 1/sqrt(128)

// dynamic-LDS float offsets for hr_main (total 35968 floats = 143872 B)
#define L_WV    0        // wv[16][2048]            : 32768 floats (128 KB)
#define L_SCAT  32768    // scat[32 tok][20 w][4 c] : 2560 floats (10 KB)
#define L_RED   35328    // red2[32 tok][20 w]      : 640 floats
#define L_TOTF  35968
#define L_BYTES (L_TOTF * 4)

// ---------------------------------------------------------------------------
// async 16B global -> LDS (global_load_lds_dwordx4); lane l passes base+16*l.
// ---------------------------------------------------------------------------
__device__ __forceinline__ void async16(const float* g, float* l) {
    __builtin_amdgcn_global_load_lds(
        (const __attribute__((address_space(1))) void*)g,
        (__attribute__((address_space(3))) void*)l, 16, 0, 0);
}

// ---------------------------------------------------------------------------
// Precompute kernel: 17 blocks x 256 threads (unchanged, known-good).
// ---------------------------------------------------------------------------
__global__ __launch_bounds__(256) void hr_pre2(
    const float* __restrict__ ee, const float* __restrict__ gam,
    const float* __restrict__ bta, const float* __restrict__ w2,
    const float* __restrict__ b2, const float* __restrict__ wq,
    const float* __restrict__ wk, float* __restrict__ ws)
{
    const int tid  = threadIdx.x;
    const int bx   = blockIdx.x;
    const int lane = tid & 63;
    const int wave = tid >> 6;

    if (bx == 16) {
        __shared__ float sacc[26];
        if (tid < 26) sacc[tid] = 0.f;
        __syncthreads();
        float pa[26];
        #pragma unroll
        for (int j = 0; j < 26; ++j) pa[j] = 0.f;
        for (int i = tid; i < 2048; i += 256) {
            float b = b2[i];
            float4 w4 = *(const float4*)(w2 + i * 4);
            float wr[4] = {w4.x, w4.y, w4.z, w4.w};
            pa[0] += b;
            pa[1] += b * b;
            #pragma unroll
            for (int r = 0; r < 4; ++r) {
                pa[2 + r] += wr[r];
                pa[6 + r] += b * wr[r];
                #pragma unroll
                for (int r2 = 0; r2 < 4; ++r2) pa[10 + r * 4 + r2] += wr[r] * wr[r2];
            }
        }
        #pragma unroll
        for (int j = 0; j < 26; ++j) {
            float v = pa[j];
            v += __shfl_xor(v, 32); v += __shfl_xor(v, 16); v += __shfl_xor(v, 8);
            v += __shfl_xor(v, 4);  v += __shfl_xor(v, 2);  v += __shfl_xor(v, 1);
            if (lane == 0) atomicAdd(&sacc[j], v);
        }
        __syncthreads();
        if (tid < 26) ws[WS_SCAL + tid] = sacc[tid] * (1.f / 2048.f);
        return;
    }

    const int e2 = bx;
    __shared__ float sge[128];
    __shared__ float sK[128];
    __shared__ float sWqK[128];
    __shared__ float sred[8];

    float v8[8];
    float s = 0.f;
    #pragma unroll
    for (int j = 0; j < 8; ++j) { v8[j] = ee[tid + j * 256]; s += v8[j]; }
    s += __shfl_xor(s, 32); s += __shfl_xor(s, 16); s += __shfl_xor(s, 8);
    s += __shfl_xor(s, 4);  s += __shfl_xor(s, 2);  s += __shfl_xor(s, 1);
    if (lane == 0) sred[wave] = s;
    __syncthreads();
    const float mu = (sred[0] + sred[1] + sred[2] + sred[3]) * (1.f / 2048.f);
    float q = 0.f;
    #pragma unroll
    for (int j = 0; j < 8; ++j) { float d = v8[j] - mu; q += d * d; }
    q += __shfl_xor(q, 32); q += __shfl_xor(q, 16); q += __shfl_xor(q, 8);
    q += __shfl_xor(q, 4);  q += __shfl_xor(q, 2);  q += __shfl_xor(q, 1);
    if (lane == 0) sred[4 + wave] = q;
    __syncthreads();
    const float rsq = rsqrtf((sred[4] + sred[5] + sred[6] + sred[7]) * (1.f / 2048.f) + 1e-5f);

    if (tid < 128) {
        int idx = (e2 << 7) + tid;
        sge[tid] = (ee[idx] - mu) * rsq * gam[idx] + bta[idx];
    }
    __syncthreads();

    {
        int a = tid >> 1, half = tid & 1;
        const float* wr = wk + (a << 7) + (half << 6);
        const float* gg = sge + (half << 6);
        float acc = 0.f;
        #pragma unroll 8
        for (int j = 0; j < 64; ++j) acc = fmaf(gg[j], wr[j], acc);
        acc += __shfl_xor(acc, 1);
        if (half == 0) sK[a] = acc;
    }
    __syncthreads();

    {
        int d = tid >> 1, half = tid & 1;
        float acc = 0.f;
        #pragma unroll 8
        for (int j = 0; j < 64; ++j) {
            int a = (half << 6) + j;
            acc = fmaf(wq[(a << 7) + d], sK[a], acc);
        }
        acc += __shfl_xor(acc, 1);
        if (half == 0) sWqK[d] = acc;
    }
    __syncthreads();

    {
        int o = tid >> 2, qd = tid & 3;
        int r = o >> 4, e = o & 15;
        float acc = 0.f;
        #pragma unroll 8
        for (int j = 0; j < 32; ++j) {
            int d  = (qd << 5) + j;
            int ed = (e << 7) + d;
            acc = fmaf(w2[ed * 4 + r] * gam[ed], sWqK[d], acc);
        }
        acc += __shfl_xor(acc, 1);
        acc += __shfl_xor(acc, 2);
        if (qd == 0) ws[WS_PKT + (e2 << 6) + (r << 4) + e] = acc;
    }

    if (tid < 192) {
        int kind = tid >> 6;
        int e    = (tid >> 2) & 15;
        int qd   = tid & 3;
        float acc = 0.f;
        #pragma unroll 8
        for (int j = 0; j < 32; ++j) {
            int d  = (qd << 5) + j;
            int ed = (e << 7) + d;
            float w = sWqK[d];
            float t = (kind == 0) ? b2[ed] * gam[ed]
                    : (kind == 1) ? gam[ed]
                                  : bta[ed];
            acc = fmaf(t, w, acc);
        }
        acc += __shfl_xor(acc, 1);
        acc += __shfl_xor(acc, 2);
        if (qd == 0) ws[WS_D1K + (kind << 8) + (e2 << 4) + e] = acc;
    }
}

// ---------------------------------------------------------------------------
// Main kernel v7: 512 blocks x 512 thr (8 waves), 32 tokens/block (4/wave).
// The 16 Wv rows (128 KB) are staged into LDS ONCE per block; the K-loop has
// ZERO barriers and ZERO shared-memory writes — each wave independently
// streams its own 4 tokens' hidden + the 4 w1 rows from global (prefetched
// one chunk ahead) and reads Wv from conflict-free LDS. Waves drift freely,
// so latency is hidden by ILP + TLP instead of a phase-locked pipeline
// (R5/R6 showed barrier-cadence structures plateau at ~71 us).
// 1 block/CU (140.5 KB dynamic LDS), grid = 2 clean rounds of 256.
// ---------------------------------------------------------------------------
extern __shared__ float lds[];

__global__ __launch_bounds__(512) void hr_main(
    const float* __restrict__ hidden, const float* __restrict__ wv,
    const float* __restrict__ wvb, const float* __restrict__ w1,
    const float* __restrict__ b1, const float* __restrict__ tab,
    float* __restrict__ out)
{
    const int tid  = threadIdx.x;
    const int wave = tid >> 6;
    const int lane = tid & 63;
    const int l4   = lane << 2;
    const int tok0 = (blockIdx.x << 5) + (wave << 2);
    const float* hb = hidden + (size_t)tok0 * INDIM + l4;

    // ---- stage Wv[16][2048] into LDS once: wave w stages rows 2w, 2w+1 ----
    #pragma unroll
    for (int rr = 0; rr < 2; ++rr) {
        const int r = (wave << 1) + rr;
        #pragma unroll
        for (int j = 0; j < 8; ++j) {
            async16(wv + (r << 11) + (j << 8) + l4,
                    &lds[L_WV + (r << 11) + (j << 8) + l4]);
        }
    }

    float acc[NROWS][4];
    #pragma unroll
    for (int w = 0; w < NROWS; ++w) {
        acc[w][0] = 0.f; acc[w][1] = 0.f; acc[w][2] = 0.f; acc[w][3] = 0.f;
    }

    // prefetch chunk 0 (hidden 4 tokens + w1 4 rows) into registers
    float4 hc[4], wc[4], hn[4], wn[4];
    #pragma unroll
    for (int t = 0; t < 4; ++t) hc[t] = *(const float4*)(hb + t * INDIM);
    #pragma unroll
    for (int r = 0; r < 4; ++r) wc[r] = *(const float4*)(w1 + (r << 11) + l4);

    __syncthreads();   // drain staging DMAs (vmcnt 0) + chunk-0 regs; one-time

    for (int c = 0; c < 8; ++c) {
        const int coff = ((c + 1) & 7) << 8;
        // prefetch next chunk (wraps harmlessly on last iter; values unused)
        #pragma unroll
        for (int t = 0; t < 4; ++t) hn[t] = *(const float4*)(hb + t * INDIM + coff);
        #pragma unroll
        for (int r = 0; r < 4; ++r) wn[r] = *(const float4*)(w1 + (r << 11) + coff + l4);

        // compute chunk c: Wv rows from LDS (conflict-free b128), w1 from regs
        const int cbase = L_WV + (c << 8) + l4;
        #pragma unroll
        for (int r = 0; r < 16; ++r) {
            float4 wf = *(const float4*)&lds[cbase + (r << 11)];
            #pragma unroll
            for (int t = 0; t < 4; ++t) {
                acc[r][t] = fmaf(hc[t].x, wf.x,
                            fmaf(hc[t].y, wf.y,
                            fmaf(hc[t].z, wf.z,
                            fmaf(hc[t].w, wf.w, acc[r][t]))));
            }
        }
        #pragma unroll
        for (int r = 0; r < 4; ++r) {
            #pragma unroll
            for (int t = 0; t < 4; ++t) {
                acc[16 + r][t] = fmaf(hc[t].x, wc[r].x,
                                 fmaf(hc[t].y, wc[r].y,
                                 fmaf(hc[t].z, wc[r].z,
                                 fmaf(hc[t].w, wc[r].w, acc[16 + r][t]))));
            }
        }
        #pragma unroll
        for (int t = 0; t < 4; ++t) hc[t] = hn[t];
        #pragma unroll
        for (int r = 0; r < 4; ++r) wc[r] = wn[r];
    }

    // ---- reduction: 4 butterfly levels -> 4 partials (class = lane&3) ----
    #pragma unroll
    for (int w = 0; w < NROWS; ++w) {
        #pragma unroll
        for (int t = 0; t < 4; ++t) {
            float v = acc[w][t];
            v += __shfl_xor(v, 32);
            v += __shfl_xor(v, 16);
            v += __shfl_xor(v, 8);
            v += __shfl_xor(v, 4);
            acc[w][t] = v;   // lane l holds partial for class c = l&3
        }
    }
    // scatter: lane l (c = l&3, g = l>>2) writes rows {g, 16+g if g<4}
    {
        const int c = lane & 3, g = lane >> 2;
        #pragma unroll
        for (int t = 0; t < 4; ++t) {
            const int tokw = (wave << 2) + t;
            lds[L_SCAT + (tokw * 20 + g) * 4 + c] = acc[g][t];
            if (g < 4)
                lds[L_SCAT + (tokw * 20 + 16 + g) * 4 + c] = acc[16 + g][t];
        }
    }
    __syncthreads();

    // gather: 640 (tok,w) pairs, sum 4 classes each -> red2[tok][w]
    #pragma unroll
    for (int pp = 0; pp < 2; ++pp) {
        const int p = tid + (pp << 9);
        if (p < 640) {
            float4 r0 = *(const float4*)&lds[L_SCAT + p * 4];
            lds[L_RED + p] = (r0.x + r0.y) + (r0.z + r0.w);
        }
    }
    __syncthreads();

    // ---- tail: 16 threads per token (32 tokens x 16 experts = 512) ----
    const int tok = tid >> 4;
    const int e   = tid & 15;

    float ig[16];
    #pragma unroll
    for (int j = 0; j < 16; ++j) ig[j] = lds[L_RED + tok * 20 + j] + wvb[j];
    float h[4];
    #pragma unroll
    for (int r = 0; r < 4; ++r) h[r] = fmaxf(lds[L_RED + tok * 20 + 16 + r] + b1[r], 0.f);

    float muT = tab[WS_SCAL + 0];
    float e2m = tab[WS_SCAL + 1];
    #pragma unroll
    for (int r = 0; r < 4; ++r) {
        muT = fmaf(h[r], tab[WS_SCAL + 2 + r], muT);
        e2m = fmaf(2.f * h[r], tab[WS_SCAL + 6 + r], e2m);
        #pragma unroll
        for (int r2 = 0; r2 < 4; ++r2)
            e2m = fmaf(h[r] * h[r2], tab[WS_SCAL + 10 + r * 4 + r2], e2m);
    }
    const float var = e2m - muT * muT;
    const float rsq = rsqrtf(var + 1e-5f);

    float sv[16];
    #pragma unroll
    for (int e2 = 0; e2 < 16; ++e2) {
        float s = tab[WS_D1K + (e2 << 4) + e];
        s = fmaf(h[0], tab[(e2 << 6) + e], s);
        s = fmaf(h[1], tab[(e2 << 6) + 16 + e], s);
        s = fmaf(h[2], tab[(e2 << 6) + 32 + e], s);
        s = fmaf(h[3], tab[(e2 << 6) + 48 + e], s);
        s = fmaf(-muT, tab[WS_GQK + (e2 << 4) + e], s);
        sv[e2] = (rsq * s + tab[WS_BQK + (e2 << 4) + e]) * SIM_SCALE;
    }
    float mx = sv[0];
    #pragma unroll
    for (int e2 = 1; e2 < 16; ++e2) mx = fmaxf(mx, sv[e2]);
    float den = 0.f, gate = 0.f;
    #pragma unroll
    for (int e2 = 0; e2 < 16; ++e2) {
        float p = __expf(sv[e2] - mx);
        den += p;
        gate = fmaf(p, ig[e2], gate);
    }
    gate /= den;

    float gm = gate;
    gm = fmaxf(gm, __shfl_xor(gm, 1));
    gm = fmaxf(gm, __shfl_xor(gm, 2));
    gm = fmaxf(gm, __shfl_xor(gm, 4));
    gm = fmaxf(gm, __shfl_xor(gm, 8));
    float ex = __expf(gate - gm);
    float es = ex;
    es += __shfl_xor(es, 1);
    es += __shfl_xor(es, 2);
    es += __shfl_xor(es, 4);
    es += __shfl_xor(es, 8);
    const float rw = ex / es;

    float v1 = rw; int i1 = e;
    #pragma unroll
    for (int m = 1; m <= 8; m <<= 1) {
        float ov = __shfl_xor(v1, m);
        int   oi = __shfl_xor(i1, m);
        if (ov > v1 || (ov == v1 && oi < i1)) { v1 = ov; i1 = oi; }
    }
    float v2 = (e == i1) ? -INFINITY : rw; int i2 = e;
    #pragma unroll
    for (int m = 1; m <= 8; m <<= 1) {
        float ov = __shfl_xor(v2, m);
        int   oi = __shfl_xor(i2, m);
        if (ov > v2 || (ov == v2 && oi < i2)) { v2 = ov; i2 = oi; }
    }

    float oval = 0.f;
    if (e == i1 || e == i2) {
        float t = __expf((v2 - v1) * 10.f);
        oval = (e == i1) ? (1.f / (1.f + t)) : (t / (1.f + t));
    }
    out[(((size_t)blockIdx.x << 5) + tok) * 16 + e] = oval;
}

// ---------------------------------------------------------------------------
extern "C" void kernel_launch(void* const* d_in, const int* in_sizes, int n_in,
                              void* d_out, int out_size, void* d_ws, size_t ws_size,
                              hipStream_t stream)
{
    const float* hidden = (const float*)d_in[0];   // (4,4096,2048)
    const float* ee     = (const float*)d_in[1];   // (16,128)
    const float* gam    = (const float*)d_in[2];   // (16,128)
    const float* bta    = (const float*)d_in[3];   // (16,128)
    const float* wv     = (const float*)d_in[4];   // (16,2048)
    const float* wvb    = (const float*)d_in[5];   // (16,)
    const float* w1     = (const float*)d_in[6];   // (4,2048)
    const float* b1     = (const float*)d_in[7];   // (4,)
    const float* w2     = (const float*)d_in[8];   // (2048,4)
    const float* b2     = (const float*)d_in[9];   // (2048,)
    const float* wq     = (const float*)d_in[10];  // (128,128)
    const float* wk     = (const float*)d_in[11];  // (128,128)
    float* out = (float*)d_out;
    float* ws  = (float*)d_ws;

    // allow >64 KB dynamic LDS (idempotent; not a stream op — capture-safe)
    hipFuncSetAttribute((const void*)hr_main,
                        hipFuncAttributeMaxDynamicSharedMemorySize, L_BYTES);

    hipLaunchKernelGGL(hr_pre2, dim3(17), dim3(256), 0, stream,
                       ee, gam, bta, w2, b2, wq, wk, ws);
    hipLaunchKernelGGL(hr_main, dim3(NTOK / 32), dim3(512), L_BYTES, stream,
                       hidden, wv, wvb, w1, b1, ws, out);
}